// Round 3
// baseline (226.591 us; speedup 1.0000x reference)
//
#include <hip/hip_runtime.h>

#define HIDDEN 256
#define CAP 64   // bucket capacity per node; deg ~ Poisson(16) => P(deg>=64) ~ e^-40

typedef _Float16 h4_t __attribute__((ext_vector_type(4)));
typedef _Float16 h8_t __attribute__((ext_vector_type(8)));
typedef float    f4_t __attribute__((ext_vector_type(4)));

// compile-time unroll machinery (constexpr ping-pong indices; rule #20: no runtime
// indexing into register arrays)
template<int N> struct IC { static constexpr int v = N; };
template<int...> struct Seq {};
template<int N, int... Is> struct MkSeq : MkSeq<N - 1, N - 1, Is...> {};
template<int... Is> struct MkSeq<0, Is...> { using t = Seq<Is...>; };
template<typename F, int... Is>
__device__ __forceinline__ void unroll_for(F&& f, Seq<Is...>) { (f(IC<Is>{}), ...); }

__device__ inline f4_t cvt4(h4_t h) {
    f4_t o; o.x = (float)h.x; o.y = (float)h.y; o.z = (float)h.z; o.w = (float)h.w;
    return o;
}

// ---------------- prep: bucket-fill, weights->f16, mask flags (x-conversion gone: ----
// ---------------- GEMM1 now reads x f32 directly with fused PReLU) ------------------
__global__ __launch_bounds__(256) void k_prep(
        const int* __restrict__ ei, const int* __restrict__ ea, int E,
        int* __restrict__ cnt, int* __restrict__ csr, int nb_fill,
        const float* __restrict__ W_enc, const float* __restrict__ W1,
        const float* __restrict__ W2, _Float16* __restrict__ Whenc,
        _Float16* __restrict__ Wh1, _Float16* __restrict__ Wh2, int nb_w,
        const int* __restrict__ mask, unsigned char* __restrict__ flags, int NM) {
    int b = blockIdx.x;
    int t = threadIdx.x;
    if (b < nb_fill) {
        int e = b * 256 + t;
        if (e >= E) return;
        int src = ei[e];
        int dst = ei[E + e];
        int combo = ea[2 * e] * 3 + ea[2 * e + 1];     // a1*3+a2, 0..17
        int slot = atomicAdd(&cnt[dst], 1);
        if (slot < CAP) csr[dst * CAP + slot] = src | (combo << 16);
        return;
    }
    b -= nb_fill;
    if (b < nb_w) {
        const int n0 = HIDDEN * HIDDEN, n1 = 2 * HIDDEN * HIDDEN, n2 = HIDDEN * 2 * HIDDEN;
        int base = (b * 256 + t) * 4;
        const float* s; _Float16* d; int off;
        if (base < n0) { s = W_enc; d = Whenc; off = base; }
        else if (base < n0 + n1) { s = W1; d = Wh1; off = base - n0; }
        else if (base < n0 + n1 + n2) { s = W2; d = Wh2; off = base - n0 - n1; }
        else return;
        f4_t v = *(const f4_t*)(s + off);
        h4_t o; o.x = (_Float16)v.x; o.y = (_Float16)v.y;
        o.z = (_Float16)v.z; o.w = (_Float16)v.w;
        *(h4_t*)(d + off) = o;
        return;
    }
    b -= nb_w;
    {
        int i = b * 256 + t;
        if (i < NM) flags[mask[i]] = 1;
    }
}

// ---------------- aggregation: 4 nodes / 256-thr block; csr preload + 8-wide gather --
__global__ __launch_bounds__(256) void k_aggregate(
        const _Float16* __restrict__ xe,
        const float* __restrict__ E1, const float* __restrict__ E2,
        const int* __restrict__ cnt, const int* __restrict__ csr,
        _Float16* __restrict__ aggr, int N, int Mpad) {
    __shared__ __align__(16) _Float16 e12h[18 * HIDDEN];   // 9 KB
    int t = threadIdx.x;
    for (int idx = t; idx < 18 * 64; idx += 256) {
        int combo = idx >> 6, c4 = (idx & 63) * 4;
        int a1 = combo / 3, a2 = combo - a1 * 3;
        f4_t v1 = *(const f4_t*)(E1 + a1 * HIDDEN + c4);
        f4_t v2 = *(const f4_t*)(E2 + a2 * HIDDEN + c4);
        h4_t o;
        o.x = (_Float16)(v1.x + v2.x); o.y = (_Float16)(v1.y + v2.y);
        o.z = (_Float16)(v1.z + v2.z); o.w = (_Float16)(v1.w + v2.w);
        *(h4_t*)(e12h + combo * HIDDEN + c4) = o;
    }
    __syncthreads();
    int node = blockIdx.x * 4 + (t >> 6);
    if (node >= Mpad) return;
    int lane = t & 63;
    int c0 = lane * 4;
    if (node >= N) {
        *(h4_t*)(aggr + (size_t)node * HIDDEN + c0) = (h4_t)(_Float16)0.f;
        return;
    }
    int deg = cnt[node];
    if (deg > CAP) deg = CAP;
    const int* lst = csr + (size_t)node * CAP;
    int pv = (lane < deg) ? lst[lane] : 0;        // all edge descriptors, 1 per lane

    h4_t hs = *(const h4_t*)(xe + (size_t)node * HIDDEN + c0);
    h4_t se = *(const h4_t*)(e12h + 12 * HIDDEN + c0);     // self-loop: E1[4]+E2[0]
    f4_t acc = cvt4(hs) + cvt4(se);

    int e = 0;
    for (; e + 7 < deg; e += 8) {
        int p[8]; h4_t hv[8], qv[8];
#pragma unroll
        for (int j = 0; j < 8; ++j) p[j] = __shfl(pv, e + j, 64);
#pragma unroll
        for (int j = 0; j < 8; ++j)
            hv[j] = *(const h4_t*)(xe + (size_t)(p[j] & 0xFFFF) * HIDDEN + c0);
#pragma unroll
        for (int j = 0; j < 8; ++j)
            qv[j] = *(const h4_t*)(e12h + (p[j] >> 16) * HIDDEN + c0);
        h4_t s0 = (hv[0] + qv[0]) + (hv[1] + qv[1]);   // v_pk_add_f16 trees, depth 2
        h4_t s1 = (hv[2] + qv[2]) + (hv[3] + qv[3]);
        h4_t s2 = (hv[4] + qv[4]) + (hv[5] + qv[5]);
        h4_t s3 = (hv[6] + qv[6]) + (hv[7] + qv[7]);
        acc += cvt4(s0) + cvt4(s1);
        acc += cvt4(s2) + cvt4(s3);
    }
    for (; e < deg; ++e) {
        int p = __shfl(pv, e, 64);
        h4_t h = *(const h4_t*)(xe + (size_t)(p & 0xFFFF) * HIDDEN + c0);
        h4_t q = *(const h4_t*)(e12h + (p >> 16) * HIDDEN + c0);
        acc += cvt4(h + q);
    }
    h4_t o;
    o.x = (_Float16)acc.x; o.y = (_Float16)acc.y;
    o.z = (_Float16)acc.z; o.w = (_Float16)acc.w;
    *(h4_t*)(aggr + (size_t)node * HIDDEN + c0) = o;
}

// ---------------- LDS-free register-pipelined MFMA GEMM: C = act(A @ B^T + bias) -----
// 256-thr blocks = 4 independent waves, each owning a BM(=TM*16) x 64 tile.
// Fragments load STRAIGHT from global to registers (each 16B/lane h8 load touches
// 16 fully-consumed 64B lines -- identical line count to LDS staging), ping-pong
// 2-deep: step s+1's 6 loads issue before step s's MFMAs, so the compiler's
// auto-waitcnt becomes a counted vmcnt with a full step of cover. Zero LDS, no
// barriers, no lgkmcnt -> occupancy is VGPR-capped (~4 waves/SIMD), preserving the
// TLP that R2's 32KB-LDS ring destroyed (207us regression). A_F32 fuses
// PReLU(x f32)->f16 at fragment-convert time (conversion deferred to the MFMA
// step so the prefetch stays async); kills the xh intermediate.
template <int TM, int K, bool RELU, bool HAS_BIAS, bool OUT_F16, bool MASK, bool A_F32>
__global__ __launch_bounds__(256) void k_gemm_reg(
        const void* __restrict__ Ain, const _Float16* __restrict__ B,
        const float* __restrict__ bias, void* __restrict__ Cout,
        const unsigned char* __restrict__ flags, const float* __restrict__ prelu_a,
        int Mload, int Mstore, int N) {
    constexpr int BM = TM * 16;
    constexpr int NS = K / 32;
    int t = threadIdx.x;
    int wv = t >> 6, L = t & 63;
    int m0 = (blockIdx.x * 4 + wv) * BM;
    int n0 = blockIdx.y * 64;
    int lr = L & 15, lk = (L >> 4) * 8;

    const _Float16* Ah = (const _Float16*)Ain;
    const float*    Af = (const float*)Ain;
    float pa = 0.f;
    if constexpr (A_F32) pa = *prelu_a;

    f4_t acc[TM][4] = {};
    h8_t fa[2][TM];            // f16 A fragments (ping-pong)
    f4_t fa32[2][TM][2];       // raw f32 A fragments (A_F32 path)
    h8_t fb[2][4];             // B fragments

    auto LOAD = [&](auto SC, auto BC) {
        constexpr int s = SC.v, bb = BC.v;
        const int k0 = s * 32;
#pragma unroll
        for (int i = 0; i < TM; ++i) {
            int row = m0 + i * 16 + lr;
            if constexpr (A_F32) {
                f4_t u = {0.f, 0.f, 0.f, 0.f}, v2 = {0.f, 0.f, 0.f, 0.f};
                if (row < Mload) {
                    const float* p = Af + (size_t)row * K + k0 + lk;
                    u  = *(const f4_t*)p;
                    v2 = *(const f4_t*)(p + 4);
                }
                fa32[bb][i][0] = u; fa32[bb][i][1] = v2;
            } else {
                fa[bb][i] = *(const h8_t*)(Ah + (size_t)row * K + k0 + lk);
            }
        }
#pragma unroll
        for (int j = 0; j < 4; ++j)
            fb[bb][j] = *(const h8_t*)(B + (size_t)(n0 + j * 16 + lr) * K + k0 + lk);
    };

    LOAD(IC<0>{}, IC<0>{});
    unroll_for([&](auto SC) {
        constexpr int s = SC.v, bb = s & 1;
        if constexpr (s + 1 < NS) LOAD(IC<s + 1>{}, IC<bb ^ 1>{});
        h8_t af[TM];
#pragma unroll
        for (int i = 0; i < TM; ++i) {
            if constexpr (A_F32) {
                f4_t u = fa32[bb][i][0], v2 = fa32[bb][i][1];
                h8_t o;
                o[0] = (_Float16)(u.x  >= 0.f ? u.x  : pa * u.x);
                o[1] = (_Float16)(u.y  >= 0.f ? u.y  : pa * u.y);
                o[2] = (_Float16)(u.z  >= 0.f ? u.z  : pa * u.z);
                o[3] = (_Float16)(u.w  >= 0.f ? u.w  : pa * u.w);
                o[4] = (_Float16)(v2.x >= 0.f ? v2.x : pa * v2.x);
                o[5] = (_Float16)(v2.y >= 0.f ? v2.y : pa * v2.y);
                o[6] = (_Float16)(v2.z >= 0.f ? v2.z : pa * v2.z);
                o[7] = (_Float16)(v2.w >= 0.f ? v2.w : pa * v2.w);
                af[i] = o;
            } else {
                af[i] = fa[bb][i];
            }
        }
#pragma unroll
        for (int i = 0; i < TM; ++i)
#pragma unroll
            for (int j = 0; j < 4; ++j)
                acc[i][j] = __builtin_amdgcn_mfma_f32_16x16x32_f16(af[i], fb[bb][j], acc[i][j], 0, 0, 0);
    }, typename MkSeq<NS>::t{});

    // epilogue: C/D layout col = L&15, row = (L>>4)*4 + r
    int lr4 = (L >> 4) * 4;
#pragma unroll
    for (int i = 0; i < TM; ++i)
#pragma unroll
        for (int r = 0; r < 4; ++r) {
            int row = m0 + i * 16 + lr4 + r;
            float zm = 1.f;
            if constexpr (MASK) zm = flags[row] ? 0.f : 1.f;
#pragma unroll
            for (int j = 0; j < 4; ++j) {
                int col = n0 + j * 16 + lr;
                float v = acc[i][j][r];
                if constexpr (HAS_BIAS) v += bias[col];
                if constexpr (RELU) v = v > 0.f ? v : 0.f;
                v *= zm;
                if constexpr (OUT_F16) {
                    ((_Float16*)Cout)[(size_t)row * N + col] = (_Float16)v;
                } else {
                    if (row < Mstore) ((float*)Cout)[(size_t)row * N + col] = v;
                }
            }
        }
}

extern "C" void kernel_launch(void* const* d_in, const int* in_sizes, int n_in,
                              void* d_out, int out_size, void* d_ws, size_t ws_size,
                              hipStream_t stream) {
    const float* x       = (const float*)d_in[0];
    const int*   ei      = (const int*)d_in[1];
    const int*   ea      = (const int*)d_in[2];
    const int*   mask    = (const int*)d_in[3];
    const float* prelu_a = (const float*)d_in[4];
    const float* W_enc   = (const float*)d_in[5];
    const float* E1      = (const float*)d_in[6];
    const float* E2      = (const float*)d_in[7];
    const float* W1      = (const float*)d_in[8];
    const float* b1      = (const float*)d_in[9];
    const float* W2      = (const float*)d_in[10];
    const float* b2      = (const float*)d_in[11];
    float*       out     = (float*)d_out;

    int N  = in_sizes[0] / HIDDEN;           // 20000
    int E  = in_sizes[1] / 2;                // 320000
    int NM = in_sizes[3];                    // 2000
    int Mpad = ((N + 127) / 128) * 128;      // 20096 (multiple of 128)

    char* ws = (char*)d_ws;
    size_t off = 0;
    _Float16* XEh   = (_Float16*)(ws + off); off += (size_t)Mpad * HIDDEN * 2;
    _Float16* AGh   = (_Float16*)(ws + off); off += (size_t)Mpad * HIDDEN * 2;
    _Float16* Hh    = (_Float16*)(ws + off); off += (size_t)Mpad * 2 * HIDDEN * 2;
    _Float16* Whenc = (_Float16*)(ws + off); off += (size_t)HIDDEN * HIDDEN * 2;
    _Float16* Wh1   = (_Float16*)(ws + off); off += (size_t)2 * HIDDEN * HIDDEN * 2;
    _Float16* Wh2   = (_Float16*)(ws + off); off += (size_t)HIDDEN * 2 * HIDDEN * 2;
    int* cnt        = (int*)(ws + off);      off += (size_t)N * 4;
    unsigned char* flags = (unsigned char*)(ws + off); off += (size_t)Mpad;
    off = (off + 15) & ~(size_t)15;
    int* csr        = (int*)(ws + off);      off += (size_t)N * CAP * 4;

    hipMemsetAsync(cnt, 0, (size_t)N * 4 + (size_t)Mpad, stream);   // cnt + flags

    int nb_fill = (E + 255) / 256;                   // 1250
    int wtot4   = (HIDDEN * HIDDEN + 2 * HIDDEN * HIDDEN + HIDDEN * 2 * HIDDEN) / 4;
    int nb_w    = (wtot4 + 255) / 256;               // 320
    int nb_m    = (NM + 255) / 256;                  // 8
    k_prep<<<nb_fill + nb_w + nb_m, 256, 0, stream>>>(
        ei, ea, E, cnt, csr, nb_fill,
        W_enc, W1, W2, Whenc, Wh1, Wh2, nb_w,
        mask, flags, NM);

    // GEMM1: XE = (prelu(x f32)@W_enc^T), masked rows zeroed. 128x64 blocks (4 waves).
    dim3 g1(Mpad / 128, HIDDEN / 64);
    k_gemm_reg<2, HIDDEN, false, false, true, true, true><<<g1, 256, 0, stream>>>(
        x, Whenc, nullptr, XEh, flags, prelu_a, N, N, HIDDEN);

    k_aggregate<<<(Mpad + 3) / 4, 256, 0, stream>>>(XEh, E1, E2, cnt, csr, AGh, N, Mpad);

    // GEMM2: H = relu(AG@W1^T + b1).
    dim3 g2(Mpad / 128, 2 * HIDDEN / 64);
    k_gemm_reg<2, HIDDEN, true, true, true, false, false><<<g2, 256, 0, stream>>>(
        AGh, Wh1, b1, Hh, nullptr, nullptr, Mpad, N, 2 * HIDDEN);

    // GEMM3: out = H@W2^T + b2 (f32).
    dim3 g3(Mpad / 128, HIDDEN / 64);
    k_gemm_reg<2, 2 * HIDDEN, false, true, false, false, false><<<g3, 256, 0, stream>>>(
        Hh, Wh2, b2, out, nullptr, nullptr, Mpad, N, HIDDEN);
}